// Round 10
// baseline (420.911 us; speedup 1.0000x reference)
//
#include <hip/hip_runtime.h>

// ShiftWise conv: straight-line pass1 (branch-free row pairs) + bf16 stash.
// Pass1: lora1(15x3), lora2(3x15), small(3x3) per rep channel; per-(c,rb)
// sum/sumsq partials; conv outputs stored as bf16 (RNE) into d_ws.
// Row validity handled by MASKS (clamped addr + rm multiplier == zero-pad),
// not branches -> the 22-row loop is straight-line; loads for 2 rows are
// issued per iteration before any FMA (11 wait points, ~2x compute per wait).
// Reduce: fold stats into (A1,A2,A3,K).
// Pass2 = sw_norm: streaming y = A1*l1 + A2*l2 + A3*s + K + x (+ghost copy).
// Fallback (ws too small): round-4-exact recompute pass2.

#define B_    32
#define CIN   256
#define REPN  196
#define HW    56
#define IMG   3136
#define NTOT  (B_ * CIN * IMG)
#define NCONVBLK 1400   // 25 groups of 56 = (8 channels x 7 rowblocks)
#define NGHOSTBLK 1920  // 60 ghost channels x 32 batches
#define STASH_ELEMS (B_ * REPN * IMG)

__device__ __forceinline__ void load_row20(float (&w)[20], const float* __restrict__ in,
                                           int base) {
  int i0 = base;      i0 = i0 < 0 ? 0 : i0;
  int i1 = base + 4;  i1 = i1 < 0 ? 0 : i1;
  int i3 = base + 12; i3 = i3 > (NTOT - 4) ? (NTOT - 4) : i3;
  int i4 = base + 16; i4 = i4 > (NTOT - 4) ? (NTOT - 4) : i4;
  const float4 v0 = *reinterpret_cast<const float4*>(in + i0);
  const float4 v1 = *reinterpret_cast<const float4*>(in + i1);
  const float4 v2 = *reinterpret_cast<const float4*>(in + base + 8);
  const float4 v3 = *reinterpret_cast<const float4*>(in + i3);
  const float4 v4 = *reinterpret_cast<const float4*>(in + i4);
  w[0]=v0.x;  w[1]=v0.y;  w[2]=v0.z;  w[3]=v0.w;
  w[4]=v1.x;  w[5]=v1.y;  w[6]=v1.z;  w[7]=v1.w;
  w[8]=v2.x;  w[9]=v2.y;  w[10]=v2.z; w[11]=v2.w;
  w[12]=v3.x; w[13]=v3.y; w[14]=v3.z; w[15]=v3.w;
  w[16]=v4.x; w[17]=v4.y; w[18]=v4.z; w[19]=v4.w;
}

__device__ __forceinline__ unsigned short pack_bf16(float f) {
  unsigned int u = __float_as_uint(f);
  u = u + 0x7FFFu + ((u >> 16) & 1u);   // RNE
  return (unsigned short)(u >> 16);
}

// ---------- Pass1: branch-free paired-row conv + stats + bf16 stash ----------
template <bool STASH>
__launch_bounds__(448, 4)
__global__ void sw_pass1(const float* __restrict__ in, const int* __restrict__ rep_idx,
                         const float* __restrict__ wsum, float* __restrict__ partial,
                         unsigned short* __restrict__ L1, unsigned short* __restrict__ L2,
                         unsigned short* __restrict__ S3) {
  const int bid = blockIdx.x;
  const int tid = threadIdx.x;

  const int c = (bid / 56) * 8 + (bid & 7);
  const int rb = (bid % 56) >> 3;
  if (c >= REPN) return;
  const int h0 = rb * 8;

  const int b = tid / 14;        // 0..31
  const int tw = tid - b * 14;   // 0..13
  const int w0 = tw * 4;
  const int src_c = rep_idx[c];
  const int ibase = (b * CIN + src_c) * IMG;
  const int sbase = (b * REPN + c) * IMG;

  float wv[45];
  #pragma unroll
  for (int j = 0; j < 45; ++j) wv[j] = wsum[c * 45 + j];

  const float ma = (tw >= 2) ? 1.f : 0.f;
  const float mb = (tw >= 1) ? 1.f : 0.f;
  const float mc = (tw <= 12) ? 1.f : 0.f;
  const float md = (tw <= 11) ? 1.f : 0.f;

  float acc1[8][4] = {};
  float acc2[3][4] = {};
  float acc3[3][4] = {};
  float s1 = 0, q1 = 0, s2 = 0, q2 = 0, s3 = 0, q3 = 0;

  #pragma unroll
  for (int sp = 0; sp < 11; ++sp) {
    // ---- issue BOTH rows' loads up front (unconditional -> registers) ----
    const int sA = 2 * sp, sB = 2 * sp + 1;
    const int rA0 = h0 - 6 + sA, rB0 = h0 - 6 + sB;
    const float rmA = (rA0 >= 0 && rA0 < HW) ? 1.f : 0.f;
    const float rmB = (rB0 >= 0 && rB0 < HW) ? 1.f : 0.f;
    const int rA = rA0 < 0 ? 0 : (rA0 > 55 ? 55 : rA0);
    const int rB = rB0 < 0 ? 0 : (rB0 > 55 ? 55 : rB0);
    float wA[20], wB[20];
    load_row20(wA, in, ibase + rA * HW + w0 - 8);
    load_row20(wB, in, ibase + rB * HW + w0 - 8);

    // ================= row A =================
    {
      const int s = sA;
      const float f0 = ma * rmA, f1 = mb * rmA, f2 = rmA, f3 = mc * rmA, f4 = md * rmA;
      float win[20];
      #pragma unroll
      for (int e = 0; e < 4; ++e)  win[e] = wA[e] * f0;
      #pragma unroll
      for (int e = 4; e < 8; ++e)  win[e] = wA[e] * f1;
      #pragma unroll
      for (int e = 8; e < 12; ++e) win[e] = wA[e] * f2;
      #pragma unroll
      for (int e = 12; e < 16; ++e) win[e] = wA[e] * f3;
      #pragma unroll
      for (int e = 16; e < 20; ++e) win[e] = wA[e] * f4;

      #pragma unroll
      for (int lr = 0; lr < 8; ++lr) {
        const int t = s - lr;
        if (t >= 0 && t < 15) {
          #pragma unroll
          for (int kw = 0; kw < 3; ++kw) {
            const float wgt = wv[3 * t + kw];
            #pragma unroll
            for (int dw = 0; dw < 4; ++dw)
              acc1[lr][dw] = fmaf(win[dw + kw + 7], wgt, acc1[lr][dw]);
          }
        }
      }
      #pragma unroll
      for (int lr = 0; lr < 8; ++lr) {
        const int kh = s - lr - 5;
        if (kh >= 0 && kh < 3) {
          #pragma unroll
          for (int T = 0; T < 15; ++T) {
            const float wgt = wv[(T / 3) * 9 + kh * 3 + (T % 3)];
            #pragma unroll
            for (int dw = 0; dw < 4; ++dw)
              acc2[lr % 3][dw] = fmaf(win[dw + T + 2], wgt, acc2[lr % 3][dw]);
          }
          #pragma unroll
          for (int kw = 0; kw < 3; ++kw) {
            const float wgt = wv[18 + kh * 3 + kw];
            #pragma unroll
            for (int dw = 0; dw < 4; ++dw)
              acc3[lr % 3][dw] = fmaf(win[dw + kw + 7], wgt, acc3[lr % 3][dw]);
          }
        }
      }
      if (s >= 14) {               // fold1
        const int lr = s - 14;
        #pragma unroll
        for (int dw = 0; dw < 4; ++dw) {
          const float v = acc1[lr][dw];
          s1 += v; q1 = fmaf(v, v, q1);
        }
        if (STASH) {
          ushort4 t4;
          t4.x = pack_bf16(acc1[lr][0]); t4.y = pack_bf16(acc1[lr][1]);
          t4.z = pack_bf16(acc1[lr][2]); t4.w = pack_bf16(acc1[lr][3]);
          *reinterpret_cast<ushort4*>(L1 + sbase + (h0 + lr) * HW + w0) = t4;
        }
      }
      if (s >= 7 && s <= 14) {     // fold2
        const int lr = s - 7;
        if (STASH) {
          ushort4 t2, t3;
          t2.x = pack_bf16(acc2[lr % 3][0]); t2.y = pack_bf16(acc2[lr % 3][1]);
          t2.z = pack_bf16(acc2[lr % 3][2]); t2.w = pack_bf16(acc2[lr % 3][3]);
          t3.x = pack_bf16(acc3[lr % 3][0]); t3.y = pack_bf16(acc3[lr % 3][1]);
          t3.z = pack_bf16(acc3[lr % 3][2]); t3.w = pack_bf16(acc3[lr % 3][3]);
          *reinterpret_cast<ushort4*>(L2 + sbase + (h0 + lr) * HW + w0) = t2;
          *reinterpret_cast<ushort4*>(S3 + sbase + (h0 + lr) * HW + w0) = t3;
        }
        #pragma unroll
        for (int dw = 0; dw < 4; ++dw) {
          const float v2 = acc2[lr % 3][dw], v3 = acc3[lr % 3][dw];
          s2 += v2; q2 = fmaf(v2, v2, q2);
          s3 += v3; q3 = fmaf(v3, v3, q3);
          acc2[lr % 3][dw] = 0.f;
          acc3[lr % 3][dw] = 0.f;
        }
      }
    }
    // ================= row B =================
    {
      const int s = sB;
      const float f0 = ma * rmB, f1 = mb * rmB, f2 = rmB, f3 = mc * rmB, f4 = md * rmB;
      float win[20];
      #pragma unroll
      for (int e = 0; e < 4; ++e)  win[e] = wB[e] * f0;
      #pragma unroll
      for (int e = 4; e < 8; ++e)  win[e] = wB[e] * f1;
      #pragma unroll
      for (int e = 8; e < 12; ++e) win[e] = wB[e] * f2;
      #pragma unroll
      for (int e = 12; e < 16; ++e) win[e] = wB[e] * f3;
      #pragma unroll
      for (int e = 16; e < 20; ++e) win[e] = wB[e] * f4;

      #pragma unroll
      for (int lr = 0; lr < 8; ++lr) {
        const int t = s - lr;
        if (t >= 0 && t < 15) {
          #pragma unroll
          for (int kw = 0; kw < 3; ++kw) {
            const float wgt = wv[3 * t + kw];
            #pragma unroll
            for (int dw = 0; dw < 4; ++dw)
              acc1[lr][dw] = fmaf(win[dw + kw + 7], wgt, acc1[lr][dw]);
          }
        }
      }
      #pragma unroll
      for (int lr = 0; lr < 8; ++lr) {
        const int kh = s - lr - 5;
        if (kh >= 0 && kh < 3) {
          #pragma unroll
          for (int T = 0; T < 15; ++T) {
            const float wgt = wv[(T / 3) * 9 + kh * 3 + (T % 3)];
            #pragma unroll
            for (int dw = 0; dw < 4; ++dw)
              acc2[lr % 3][dw] = fmaf(win[dw + T + 2], wgt, acc2[lr % 3][dw]);
          }
          #pragma unroll
          for (int kw = 0; kw < 3; ++kw) {
            const float wgt = wv[18 + kh * 3 + kw];
            #pragma unroll
            for (int dw = 0; dw < 4; ++dw)
              acc3[lr % 3][dw] = fmaf(win[dw + kw + 7], wgt, acc3[lr % 3][dw]);
          }
        }
      }
      if (s >= 14) {               // fold1
        const int lr = s - 14;
        #pragma unroll
        for (int dw = 0; dw < 4; ++dw) {
          const float v = acc1[lr][dw];
          s1 += v; q1 = fmaf(v, v, q1);
        }
        if (STASH) {
          ushort4 t4;
          t4.x = pack_bf16(acc1[lr][0]); t4.y = pack_bf16(acc1[lr][1]);
          t4.z = pack_bf16(acc1[lr][2]); t4.w = pack_bf16(acc1[lr][3]);
          *reinterpret_cast<ushort4*>(L1 + sbase + (h0 + lr) * HW + w0) = t4;
        }
      }
      if (s >= 7 && s <= 14) {     // fold2
        const int lr = s - 7;
        if (STASH) {
          ushort4 t2, t3;
          t2.x = pack_bf16(acc2[lr % 3][0]); t2.y = pack_bf16(acc2[lr % 3][1]);
          t2.z = pack_bf16(acc2[lr % 3][2]); t2.w = pack_bf16(acc2[lr % 3][3]);
          t3.x = pack_bf16(acc3[lr % 3][0]); t3.y = pack_bf16(acc3[lr % 3][1]);
          t3.z = pack_bf16(acc3[lr % 3][2]); t3.w = pack_bf16(acc3[lr % 3][3]);
          *reinterpret_cast<ushort4*>(L2 + sbase + (h0 + lr) * HW + w0) = t2;
          *reinterpret_cast<ushort4*>(S3 + sbase + (h0 + lr) * HW + w0) = t3;
        }
        #pragma unroll
        for (int dw = 0; dw < 4; ++dw) {
          const float v2 = acc2[lr % 3][dw], v3 = acc3[lr % 3][dw];
          s2 += v2; q2 = fmaf(v2, v2, q2);
          s3 += v3; q3 = fmaf(v3, v3, q3);
          acc2[lr % 3][dw] = 0.f;
          acc3[lr % 3][dw] = 0.f;
        }
      }
    }
  }

  __shared__ float red[7][6];
  #pragma unroll
  for (int off = 32; off > 0; off >>= 1) {
    s1 += __shfl_down(s1, off); q1 += __shfl_down(q1, off);
    s2 += __shfl_down(s2, off); q2 += __shfl_down(q2, off);
    s3 += __shfl_down(s3, off); q3 += __shfl_down(q3, off);
  }
  const int lane = tid & 63, wid = tid >> 6;
  if (lane == 0) {
    red[wid][0] = s1; red[wid][1] = q1; red[wid][2] = s2;
    red[wid][3] = q2; red[wid][4] = s3; red[wid][5] = q3;
  }
  __syncthreads();
  if (tid < 6) {
    float t = 0;
    #pragma unroll
    for (int w = 0; w < 7; ++w) t += red[w][tid];
    partial[(c * 7 + rb) * 6 + tid] = t;
  }
}

// ---------- Fallback pass2: r4-exact recompute (unused when ws fits) ----------
__launch_bounds__(448)
__global__ void sw_pass2r(const float* __restrict__ in, const int* __restrict__ rep_idx,
                          const int* __restrict__ ghost_idx, const float* __restrict__ wsum,
                          const float* __restrict__ stats2, float* __restrict__ out) {
  const int bid = blockIdx.x;
  const int tid = threadIdx.x;

  if (bid >= NCONVBLK) {
    const int g = bid - NCONVBLK;
    const int j = g >> 5, b = g & 31;
    const int src_c = ghost_idx[j];
    const float4* s = reinterpret_cast<const float4*>(in + (size_t)(b * CIN + src_c) * IMG);
    float4* d = reinterpret_cast<float4*>(out + ((size_t)(b * CIN) + REPN + j) * IMG);
    #pragma unroll 1
    for (int i = tid; i < 784; i += 448) d[i] = s[i];
    return;
  }

  const int c = (bid / 56) * 8 + (bid & 7);
  const int rb = (bid % 56) >> 3;
  if (c >= REPN) return;
  const int h0 = rb * 8;

  const int b = tid / 14;
  const int tw = tid - b * 14;
  const int w0 = tw * 4;
  const int src_c = rep_idx[c];
  const int ibase = (b * CIN + src_c) * IMG;

  float wv[45];
  #pragma unroll
  for (int j = 0; j < 45; ++j) wv[j] = wsum[c * 45 + j];

  const float A1 = stats2[c * 4 + 0], A2 = stats2[c * 4 + 1];
  const float A3 = stats2[c * 4 + 2], K_ = stats2[c * 4 + 3];

  const float ma = (tw >= 2) ? 1.f : 0.f;
  const float mb = (tw >= 1) ? 1.f : 0.f;
  const float mc = (tw <= 12) ? 1.f : 0.f;
  const float md = (tw <= 11) ? 1.f : 0.f;

  float acc1[8][4] = {};
  float acc2[3][4] = {};
  float acc3[3][4] = {};
  float stash[7][4];

  #pragma unroll
  for (int s = 0; s < 22; ++s) {
    const int r = h0 - 6 + s;
    if (r >= 0 && r < HW) {
      float win[20];
      load_row20(win, in, ibase + r * HW + w0 - 8);
      #pragma unroll
      for (int e = 0; e < 4; ++e) win[e] *= ma;
      #pragma unroll
      for (int e = 4; e < 8; ++e) win[e] *= mb;
      #pragma unroll
      for (int e = 12; e < 16; ++e) win[e] *= mc;
      #pragma unroll
      for (int e = 16; e < 20; ++e) win[e] *= md;

      #pragma unroll
      for (int lr = 0; lr < 8; ++lr) {
        const int t = s - lr;
        if (t >= 0 && t < 15) {
          #pragma unroll
          for (int kw = 0; kw < 3; ++kw) {
            const float wgt = wv[3 * t + kw];
            #pragma unroll
            for (int dw = 0; dw < 4; ++dw)
              acc1[lr][dw] = fmaf(win[dw + kw + 7], wgt, acc1[lr][dw]);
          }
        }
      }
      #pragma unroll
      for (int lr = 0; lr < 8; ++lr) {
        const int kh = s - lr - 5;
        if (kh >= 0 && kh < 3) {
          #pragma unroll
          for (int T = 0; T < 15; ++T) {
            const float wgt = wv[(T / 3) * 9 + kh * 3 + (T % 3)];
            #pragma unroll
            for (int dw = 0; dw < 4; ++dw)
              acc2[lr % 3][dw] = fmaf(win[dw + T + 2], wgt, acc2[lr % 3][dw]);
          }
          #pragma unroll
          for (int kw = 0; kw < 3; ++kw) {
            const float wgt = wv[18 + kh * 3 + kw];
            #pragma unroll
            for (int dw = 0; dw < 4; ++dw)
              acc3[lr % 3][dw] = fmaf(win[dw + kw + 7], wgt, acc3[lr % 3][dw]);
          }
        }
      }
    }

    if (s >= 14) {
      const int lr = s - 14;
      const int hh = h0 + lr;
      const float4 xv = *reinterpret_cast<const float4*>(in + ibase + hh * HW + w0);
      float4 o;
      o.x = fmaf(A1, acc1[lr][0], stash[lr % 7][0] + K_ + xv.x);
      o.y = fmaf(A1, acc1[lr][1], stash[lr % 7][1] + K_ + xv.y);
      o.z = fmaf(A1, acc1[lr][2], stash[lr % 7][2] + K_ + xv.z);
      o.w = fmaf(A1, acc1[lr][3], stash[lr % 7][3] + K_ + xv.w);
      *reinterpret_cast<float4*>(out + (size_t)(b * CIN + c) * IMG + hh * HW + w0) = o;
    }
    if (s >= 7 && s <= 14) {
      const int lr = s - 7;
      #pragma unroll
      for (int dw = 0; dw < 4; ++dw) {
        stash[lr % 7][dw] = fmaf(A2, acc2[lr % 3][dw], A3 * acc3[lr % 3][dw]);
        acc2[lr % 3][dw] = 0.f;
        acc3[lr % 3][dw] = 0.f;
      }
    }
  }
}

// ---------- Fast pass2: streaming normalize from bf16 stash ----------
__launch_bounds__(256)
__global__ void sw_norm(const float* __restrict__ in, const int* __restrict__ rep_idx,
                        const int* __restrict__ ghost_idx, const float* __restrict__ stats2,
                        const unsigned short* __restrict__ L1,
                        const unsigned short* __restrict__ L2,
                        const unsigned short* __restrict__ S3,
                        float* __restrict__ out) {
  const int bid = blockIdx.x;
  const int tid = threadIdx.x;
  if (bid >= 6272) {  // ghost copy
    const int g = bid - 6272;
    const int j = g >> 5, b = g & 31;
    const int src_c = ghost_idx[j];
    const float4* s = reinterpret_cast<const float4*>(in + (size_t)(b * CIN + src_c) * IMG);
    float4* d = reinterpret_cast<float4*>(out + ((size_t)(b * CIN) + REPN + j) * IMG);
    #pragma unroll 1
    for (int i = tid; i < 784; i += 256) d[i] = s[i];
    return;
  }
  const int c = bid >> 5, b = bid & 31;
  const float A1 = stats2[c * 4 + 0], A2 = stats2[c * 4 + 1];
  const float A3 = stats2[c * 4 + 2], K_ = stats2[c * 4 + 3];
  const int xb4 = (b * CIN + rep_idx[c]) * IMG / 4;
  const int ob4 = (b * CIN + c) * IMG / 4;
  const int sb4 = (b * REPN + c) * IMG / 4;
  const float4* xp = reinterpret_cast<const float4*>(in) + xb4;
  float4* op = reinterpret_cast<float4*>(out) + ob4;
  const ushort4* l1p = reinterpret_cast<const ushort4*>(L1) + sb4;
  const ushort4* l2p = reinterpret_cast<const ushort4*>(L2) + sb4;
  const ushort4* s3p = reinterpret_cast<const ushort4*>(S3) + sb4;
  #pragma unroll 1
  for (int g = tid; g < 784; g += 256) {
    const float4 x = xp[g];
    const ushort4 a = l1p[g], d2 = l2p[g], d3 = s3p[g];
    float4 y;
    y.x = fmaf(A1, __uint_as_float((unsigned)a.x << 16),
          fmaf(A2, __uint_as_float((unsigned)d2.x << 16),
          fmaf(A3, __uint_as_float((unsigned)d3.x << 16), K_ + x.x)));
    y.y = fmaf(A1, __uint_as_float((unsigned)a.y << 16),
          fmaf(A2, __uint_as_float((unsigned)d2.y << 16),
          fmaf(A3, __uint_as_float((unsigned)d3.y << 16), K_ + x.y)));
    y.z = fmaf(A1, __uint_as_float((unsigned)a.z << 16),
          fmaf(A2, __uint_as_float((unsigned)d2.z << 16),
          fmaf(A3, __uint_as_float((unsigned)d3.z << 16), K_ + x.z)));
    y.w = fmaf(A1, __uint_as_float((unsigned)a.w << 16),
          fmaf(A2, __uint_as_float((unsigned)d2.w << 16),
          fmaf(A3, __uint_as_float((unsigned)d3.w << 16), K_ + x.w)));
    op[g] = y;
  }
}

extern "C" __global__ void sw_prep(const float* __restrict__ w1, const float* __restrict__ w2,
                                   float* __restrict__ wsum) {
  int i = blockIdx.x * 256 + threadIdx.x;
  if (i < 8820) wsum[i] = w1[i] + w2[i];
}

extern "C" __global__ void sw_reduce(
    const float* __restrict__ partial,
    const float* __restrict__ g1, const float* __restrict__ b1,
    const float* __restrict__ g2, const float* __restrict__ b2,
    const float* __restrict__ g3, const float* __restrict__ b3,
    float* __restrict__ stats2) {
  const int c = blockIdx.x;
  const int tid = threadIdx.x;
  __shared__ float sm[6];
  if (tid < 6) {
    float s = 0;
    #pragma unroll
    for (int rb = 0; rb < 7; ++rb) s += partial[(c * 7 + rb) * 6 + tid];
    sm[tid] = s;
  }
  __syncthreads();
  if (tid == 0) {
    const float N = 100352.f;
    float m1 = sm[0] / N, v1 = sm[1] / N - m1 * m1;
    float m2 = sm[2] / N, v2 = sm[3] / N - m2 * m2;
    float m3 = sm[4] / N, v3 = sm[5] / N - m3 * m3;
    float A1 = g1[c] * rsqrtf(v1 + 1e-5f);
    float A2 = g2[c] * rsqrtf(v2 + 1e-5f);
    float A3 = g3[c] * rsqrtf(v3 + 1e-5f);
    float K = b1[c] + b2[c] + b3[c] - m1 * A1 - m2 * A2 - m3 * A3;
    stats2[c * 4 + 0] = A1; stats2[c * 4 + 1] = A2;
    stats2[c * 4 + 2] = A3; stats2[c * 4 + 3] = K;
  }
}

extern "C" void kernel_launch(void* const* d_in, const int* in_sizes, int n_in,
                              void* d_out, int out_size, void* d_ws, size_t ws_size,
                              hipStream_t stream) {
  const float* in  = (const float*)d_in[0];
  const float* w1  = (const float*)d_in[1];
  const float* w2  = (const float*)d_in[2];
  const float* g1  = (const float*)d_in[3];
  const float* b1  = (const float*)d_in[4];
  const float* g2  = (const float*)d_in[5];
  const float* b2  = (const float*)d_in[6];
  const float* g3  = (const float*)d_in[7];
  const float* b3  = (const float*)d_in[8];
  const int* ghost_idx = (const int*)d_in[9];
  const int* rep_idx   = (const int*)d_in[10];
  float* out = (float*)d_out;
  float* ws  = (float*)d_ws;

  float* wsum    = ws;          // 8820 floats
  float* stats2  = ws + 8832;   // 784 floats
  float* partial = ws + 9728;   // 1372*6 floats
  unsigned short* L1 = reinterpret_cast<unsigned short*>((char*)d_ws + (1u << 18));
  unsigned short* L2 = L1 + STASH_ELEMS;
  unsigned short* S3 = L2 + STASH_ELEMS;
  const size_t need = (1u << 18) + 3ull * STASH_ELEMS * sizeof(unsigned short);

  sw_prep<<<35, 256, 0, stream>>>(w1, w2, wsum);
  if (ws_size >= need) {
    sw_pass1<true><<<NCONVBLK, 448, 0, stream>>>(in, rep_idx, wsum, partial, L1, L2, S3);
    sw_reduce<<<196, 64, 0, stream>>>(partial, g1, b1, g2, b2, g3, b3, stats2);
    sw_norm<<<6272 + NGHOSTBLK, 256, 0, stream>>>(in, rep_idx, ghost_idx, stats2,
                                                  L1, L2, S3, out);
  } else {
    sw_pass1<false><<<NCONVBLK, 448, 0, stream>>>(in, rep_idx, wsum, partial, L1, L2, S3);
    sw_reduce<<<196, 64, 0, stream>>>(partial, g1, b1, g2, b2, g3, b3, stats2);
    sw_pass2r<<<NCONVBLK + NGHOSTBLK, 448, 0, stream>>>(in, rep_idx, ghost_idx, wsum,
                                                        stats2, out);
  }
}

// Round 11
// 178.853 us; speedup vs baseline: 2.3534x; 2.3534x over previous
//
#include <hip/hip_runtime.h>

// ShiftWise conv: pass1 = paired-row straight-line conv (NO VGPR cap, 256-thr
// blocks) + bf16 stash; pass2 = streaming normalize.
// lora1(15x3), lora2(3x15), small(3x3) per rep channel, BN'd with batch
// stats, + rep_x residual; ghost channels copied through.
// Pass1 issues 10 unconditional clamped float4 loads (2 rows) per iteration,
// consumed in-iteration with static indices (no scratch risk), then ~500 cyc
// of FMAs: 11 wait points/image instead of 22. Row validity via clamp+mask
// (== zero-pad). Block = 256 thr = 16 b x 14 col strips (+32 idle lanes) ->
// 2-3 blocks/CU resident at VGPR<=170.
// Reduce folds stats into (A1,A2,A3,K); sw_norm streams
// y = A1*l1 + A2*l2 + A3*s + K + x from the bf16 stash (+ghost copy).
// Fallback (ws too small): round-4-exact recompute pass2 (448 thr).

#define B_    32
#define CIN   256
#define REPN  196
#define HW    56
#define IMG   3136
#define NTOT  (B_ * CIN * IMG)
#define NCONV1   2800   // pass1: 25 c-groups x (8 c x 14 u); u = rb*2 + bh
#define NCONV2R  1400   // fallback pass2: 25 groups x (8 c x 7 rb), 448 thr
#define NGHOSTBLK 1920  // 60 ghost channels x 32 batches
#define STASH_ELEMS (B_ * REPN * IMG)

__device__ __forceinline__ void load_row20(float (&w)[20], const float* __restrict__ in,
                                           int base) {
  int i0 = base;      i0 = i0 < 0 ? 0 : i0;
  int i1 = base + 4;  i1 = i1 < 0 ? 0 : i1;
  int i3 = base + 12; i3 = i3 > (NTOT - 4) ? (NTOT - 4) : i3;
  int i4 = base + 16; i4 = i4 > (NTOT - 4) ? (NTOT - 4) : i4;
  const float4 v0 = *reinterpret_cast<const float4*>(in + i0);
  const float4 v1 = *reinterpret_cast<const float4*>(in + i1);
  const float4 v2 = *reinterpret_cast<const float4*>(in + base + 8);
  const float4 v3 = *reinterpret_cast<const float4*>(in + i3);
  const float4 v4 = *reinterpret_cast<const float4*>(in + i4);
  w[0]=v0.x;  w[1]=v0.y;  w[2]=v0.z;  w[3]=v0.w;
  w[4]=v1.x;  w[5]=v1.y;  w[6]=v1.z;  w[7]=v1.w;
  w[8]=v2.x;  w[9]=v2.y;  w[10]=v2.z; w[11]=v2.w;
  w[12]=v3.x; w[13]=v3.y; w[14]=v3.z; w[15]=v3.w;
  w[16]=v4.x; w[17]=v4.y; w[18]=v4.z; w[19]=v4.w;
}

__device__ __forceinline__ unsigned short pack_bf16(float f) {
  unsigned int u = __float_as_uint(f);
  u = u + 0x7FFFu + ((u >> 16) & 1u);   // RNE
  return (unsigned short)(u >> 16);
}

// One masked row of conv work + folds. s_ becomes a compile-time constant
// after full unroll; all array indices static.
#define ROW_COMPUTE(s_, wrow_, rm_)                                          \
  do {                                                                       \
    const int s = (s_);                                                      \
    const float f0 = ma * (rm_), f1 = mb * (rm_), f2 = (rm_),                \
                f3 = mc * (rm_), f4 = md * (rm_);                            \
    float win[20];                                                           \
    win[0]=wrow_[0]*f0;  win[1]=wrow_[1]*f0;  win[2]=wrow_[2]*f0;  win[3]=wrow_[3]*f0; \
    win[4]=wrow_[4]*f1;  win[5]=wrow_[5]*f1;  win[6]=wrow_[6]*f1;  win[7]=wrow_[7]*f1; \
    win[8]=wrow_[8]*f2;  win[9]=wrow_[9]*f2;  win[10]=wrow_[10]*f2; win[11]=wrow_[11]*f2; \
    win[12]=wrow_[12]*f3; win[13]=wrow_[13]*f3; win[14]=wrow_[14]*f3; win[15]=wrow_[15]*f3; \
    win[16]=wrow_[16]*f4; win[17]=wrow_[17]*f4; win[18]=wrow_[18]*f4; win[19]=wrow_[19]*f4; \
    _Pragma("unroll")                                                        \
    for (int lr = 0; lr < 8; ++lr) {                                         \
      const int t = s - lr;                                                  \
      if (t >= 0 && t < 15) {                                                \
        _Pragma("unroll")                                                    \
        for (int kw = 0; kw < 3; ++kw) {                                     \
          const float wgt = wv[3 * t + kw];                                  \
          _Pragma("unroll")                                                  \
          for (int dw = 0; dw < 4; ++dw)                                     \
            acc1[lr][dw] = fmaf(win[dw + kw + 7], wgt, acc1[lr][dw]);        \
        }                                                                    \
      }                                                                      \
    }                                                                        \
    _Pragma("unroll")                                                        \
    for (int lr = 0; lr < 8; ++lr) {                                         \
      const int kh = s - lr - 5;                                             \
      if (kh >= 0 && kh < 3) {                                               \
        _Pragma("unroll")                                                    \
        for (int T = 0; T < 15; ++T) {                                       \
          const float wgt = wv[(T / 3) * 9 + kh * 3 + (T % 3)];              \
          _Pragma("unroll")                                                  \
          for (int dw = 0; dw < 4; ++dw)                                     \
            acc2[lr % 3][dw] = fmaf(win[dw + T + 2], wgt, acc2[lr % 3][dw]); \
        }                                                                    \
        _Pragma("unroll")                                                    \
        for (int kw = 0; kw < 3; ++kw) {                                     \
          const float wgt = wv[18 + kh * 3 + kw];                            \
          _Pragma("unroll")                                                  \
          for (int dw = 0; dw < 4; ++dw)                                     \
            acc3[lr % 3][dw] = fmaf(win[dw + kw + 7], wgt, acc3[lr % 3][dw]); \
        }                                                                    \
      }                                                                      \
    }                                                                        \
    if (s >= 14) {  /* fold1: lora1 row lr complete */                       \
      const int lr = s - 14;                                                 \
      _Pragma("unroll")                                                      \
      for (int dw = 0; dw < 4; ++dw) {                                       \
        const float v = acc1[lr][dw];                                        \
        s1 += v; q1 = fmaf(v, v, q1);                                        \
      }                                                                      \
      if (STASH) {                                                           \
        ushort4 t4;                                                          \
        t4.x = pack_bf16(acc1[lr][0]); t4.y = pack_bf16(acc1[lr][1]);        \
        t4.z = pack_bf16(acc1[lr][2]); t4.w = pack_bf16(acc1[lr][3]);        \
        *reinterpret_cast<ushort4*>(L1 + sbase + (h0 + lr) * HW + w0) = t4;  \
      }                                                                      \
    }                                                                        \
    if (s >= 7 && s <= 14) {  /* fold2: lora2/small row lr complete */       \
      const int lr = s - 7;                                                  \
      if (STASH) {                                                           \
        ushort4 t2, t3;                                                      \
        t2.x = pack_bf16(acc2[lr % 3][0]); t2.y = pack_bf16(acc2[lr % 3][1]); \
        t2.z = pack_bf16(acc2[lr % 3][2]); t2.w = pack_bf16(acc2[lr % 3][3]); \
        t3.x = pack_bf16(acc3[lr % 3][0]); t3.y = pack_bf16(acc3[lr % 3][1]); \
        t3.z = pack_bf16(acc3[lr % 3][2]); t3.w = pack_bf16(acc3[lr % 3][3]); \
        *reinterpret_cast<ushort4*>(L2 + sbase + (h0 + lr) * HW + w0) = t2;  \
        *reinterpret_cast<ushort4*>(S3 + sbase + (h0 + lr) * HW + w0) = t3;  \
      }                                                                      \
      _Pragma("unroll")                                                      \
      for (int dw = 0; dw < 4; ++dw) {                                       \
        const float v2 = acc2[lr % 3][dw], v3 = acc3[lr % 3][dw];            \
        s2 += v2; q2 = fmaf(v2, v2, q2);                                     \
        s3 += v3; q3 = fmaf(v3, v3, q3);                                     \
        acc2[lr % 3][dw] = 0.f;                                              \
        acc3[lr % 3][dw] = 0.f;                                              \
      }                                                                      \
    }                                                                        \
  } while (0)

// ---------- Pass1: paired-row straight-line conv + stats + bf16 stash ----------
template <bool STASH>
__launch_bounds__(256)
__global__ void sw_pass1(const float* __restrict__ in, const int* __restrict__ rep_idx,
                         const float* __restrict__ wsum, float* __restrict__ partial,
                         unsigned short* __restrict__ L1, unsigned short* __restrict__ L2,
                         unsigned short* __restrict__ S3) {
  const int bid = blockIdx.x;
  const int tid = threadIdx.x;

  // XCD swizzle: all 14 u-blocks of channel c share bid mod 8 -> same XCD L2.
  const int c = (bid / 112) * 8 + (bid & 7);
  const int u = (bid % 112) >> 3;       // 0..13
  const int rb = u >> 1, bh = u & 1;
  if (c >= REPN) return;
  const int h0 = rb * 8;

  const int bloc = tid / 14;            // 0..18; >=16 inactive
  const int tw = tid - bloc * 14;       // 0..13
  const int w0 = tw * 4;
  const bool act = (bloc < 16);

  float wv[45];  // c block-uniform -> scalar loads
  #pragma unroll
  for (int j = 0; j < 45; ++j) wv[j] = wsum[c * 45 + j];

  float s1 = 0, q1 = 0, s2 = 0, q2 = 0, s3 = 0, q3 = 0;

  if (act) {
    const int b = bh * 16 + bloc;
    const int src_c = rep_idx[c];
    const int ibase = (b * CIN + src_c) * IMG;
    const int sbase = (b * REPN + c) * IMG;

    const float ma = (tw >= 2) ? 1.f : 0.f;
    const float mb = (tw >= 1) ? 1.f : 0.f;
    const float mc = (tw <= 12) ? 1.f : 0.f;
    const float md = (tw <= 11) ? 1.f : 0.f;

    float acc1[8][4] = {};
    float acc2[3][4] = {};
    float acc3[3][4] = {};

    #pragma unroll
    for (int sp = 0; sp < 11; ++sp) {
      const int sA = 2 * sp, sB = 2 * sp + 1;
      const int rA0 = h0 - 6 + sA, rB0 = h0 - 6 + sB;
      const float rmA = (rA0 >= 0 && rA0 < HW) ? 1.f : 0.f;
      const float rmB = (rB0 >= 0 && rB0 < HW) ? 1.f : 0.f;
      const int rA = rA0 < 0 ? 0 : (rA0 > 55 ? 55 : rA0);
      const int rB = rB0 < 0 ? 0 : (rB0 > 55 ? 55 : rB0);
      // 10 unconditional loads up front, consumed this iteration only.
      float wA[20], wB[20];
      load_row20(wA, in, ibase + rA * HW + w0 - 8);
      load_row20(wB, in, ibase + rB * HW + w0 - 8);

      ROW_COMPUTE(sA, wA, rmA);
      ROW_COMPUTE(sB, wB, rmB);
    }
  }

  __shared__ float red[4][6];
  #pragma unroll
  for (int off = 32; off > 0; off >>= 1) {
    s1 += __shfl_down(s1, off); q1 += __shfl_down(q1, off);
    s2 += __shfl_down(s2, off); q2 += __shfl_down(q2, off);
    s3 += __shfl_down(s3, off); q3 += __shfl_down(q3, off);
  }
  const int lane = tid & 63, wid = tid >> 6;
  if (lane == 0) {
    red[wid][0] = s1; red[wid][1] = q1; red[wid][2] = s2;
    red[wid][3] = q2; red[wid][4] = s3; red[wid][5] = q3;
  }
  __syncthreads();
  if (tid < 6)
    partial[(c * 14 + u) * 6 + tid] =
        red[0][tid] + red[1][tid] + red[2][tid] + red[3][tid];
}

// ---------- Fallback pass2: r4-exact recompute (used only if ws too small) ----------
__launch_bounds__(448)
__global__ void sw_pass2r(const float* __restrict__ in, const int* __restrict__ rep_idx,
                          const int* __restrict__ ghost_idx, const float* __restrict__ wsum,
                          const float* __restrict__ stats2, float* __restrict__ out) {
  const int bid = blockIdx.x;
  const int tid = threadIdx.x;

  if (bid >= NCONV2R) {
    const int g = bid - NCONV2R;
    const int j = g >> 5, b = g & 31;
    const int src_c = ghost_idx[j];
    const float4* s = reinterpret_cast<const float4*>(in + (size_t)(b * CIN + src_c) * IMG);
    float4* d = reinterpret_cast<float4*>(out + ((size_t)(b * CIN) + REPN + j) * IMG);
    #pragma unroll 1
    for (int i = tid; i < 784; i += 448) d[i] = s[i];
    return;
  }

  const int c = (bid / 56) * 8 + (bid & 7);
  const int rb = (bid % 56) >> 3;
  if (c >= REPN) return;
  const int h0 = rb * 8;

  const int b = tid / 14;
  const int tw = tid - b * 14;
  const int w0 = tw * 4;
  const int src_c = rep_idx[c];
  const int ibase = (b * CIN + src_c) * IMG;

  float wv[45];
  #pragma unroll
  for (int j = 0; j < 45; ++j) wv[j] = wsum[c * 45 + j];

  const float A1 = stats2[c * 4 + 0], A2 = stats2[c * 4 + 1];
  const float A3 = stats2[c * 4 + 2], K_ = stats2[c * 4 + 3];

  const float ma = (tw >= 2) ? 1.f : 0.f;
  const float mb = (tw >= 1) ? 1.f : 0.f;
  const float mc = (tw <= 12) ? 1.f : 0.f;
  const float md = (tw <= 11) ? 1.f : 0.f;

  float acc1[8][4] = {};
  float acc2[3][4] = {};
  float acc3[3][4] = {};
  float stash[7][4];

  #pragma unroll
  for (int s = 0; s < 22; ++s) {
    const int r = h0 - 6 + s;
    if (r >= 0 && r < HW) {
      float win[20];
      load_row20(win, in, ibase + r * HW + w0 - 8);
      #pragma unroll
      for (int e = 0; e < 4; ++e) win[e] *= ma;
      #pragma unroll
      for (int e = 4; e < 8; ++e) win[e] *= mb;
      #pragma unroll
      for (int e = 12; e < 16; ++e) win[e] *= mc;
      #pragma unroll
      for (int e = 16; e < 20; ++e) win[e] *= md;

      #pragma unroll
      for (int lr = 0; lr < 8; ++lr) {
        const int t = s - lr;
        if (t >= 0 && t < 15) {
          #pragma unroll
          for (int kw = 0; kw < 3; ++kw) {
            const float wgt = wv[3 * t + kw];
            #pragma unroll
            for (int dw = 0; dw < 4; ++dw)
              acc1[lr][dw] = fmaf(win[dw + kw + 7], wgt, acc1[lr][dw]);
          }
        }
      }
      #pragma unroll
      for (int lr = 0; lr < 8; ++lr) {
        const int kh = s - lr - 5;
        if (kh >= 0 && kh < 3) {
          #pragma unroll
          for (int T = 0; T < 15; ++T) {
            const float wgt = wv[(T / 3) * 9 + kh * 3 + (T % 3)];
            #pragma unroll
            for (int dw = 0; dw < 4; ++dw)
              acc2[lr % 3][dw] = fmaf(win[dw + T + 2], wgt, acc2[lr % 3][dw]);
          }
          #pragma unroll
          for (int kw = 0; kw < 3; ++kw) {
            const float wgt = wv[18 + kh * 3 + kw];
            #pragma unroll
            for (int dw = 0; dw < 4; ++dw)
              acc3[lr % 3][dw] = fmaf(win[dw + kw + 7], wgt, acc3[lr % 3][dw]);
          }
        }
      }
    }

    if (s >= 14) {
      const int lr = s - 14;
      const int hh = h0 + lr;
      const float4 xv = *reinterpret_cast<const float4*>(in + ibase + hh * HW + w0);
      float4 o;
      o.x = fmaf(A1, acc1[lr][0], stash[lr % 7][0] + K_ + xv.x);
      o.y = fmaf(A1, acc1[lr][1], stash[lr % 7][1] + K_ + xv.y);
      o.z = fmaf(A1, acc1[lr][2], stash[lr % 7][2] + K_ + xv.z);
      o.w = fmaf(A1, acc1[lr][3], stash[lr % 7][3] + K_ + xv.w);
      *reinterpret_cast<float4*>(out + (size_t)(b * CIN + c) * IMG + hh * HW + w0) = o;
    }
    if (s >= 7 && s <= 14) {
      const int lr = s - 7;
      #pragma unroll
      for (int dw = 0; dw < 4; ++dw) {
        stash[lr % 7][dw] = fmaf(A2, acc2[lr % 3][dw], A3 * acc3[lr % 3][dw]);
        acc2[lr % 3][dw] = 0.f;
        acc3[lr % 3][dw] = 0.f;
      }
    }
  }
}

// ---------- Fast pass2: streaming normalize from bf16 stash ----------
__launch_bounds__(256)
__global__ void sw_norm(const float* __restrict__ in, const int* __restrict__ rep_idx,
                        const int* __restrict__ ghost_idx, const float* __restrict__ stats2,
                        const unsigned short* __restrict__ L1,
                        const unsigned short* __restrict__ L2,
                        const unsigned short* __restrict__ S3,
                        float* __restrict__ out) {
  const int bid = blockIdx.x;
  const int tid = threadIdx.x;
  if (bid >= 6272) {  // ghost copy
    const int g = bid - 6272;
    const int j = g >> 5, b = g & 31;
    const int src_c = ghost_idx[j];
    const float4* s = reinterpret_cast<const float4*>(in + (size_t)(b * CIN + src_c) * IMG);
    float4* d = reinterpret_cast<float4*>(out + ((size_t)(b * CIN) + REPN + j) * IMG);
    #pragma unroll 1
    for (int i = tid; i < 784; i += 256) d[i] = s[i];
    return;
  }
  const int c = bid >> 5, b = bid & 31;
  const float A1 = stats2[c * 4 + 0], A2 = stats2[c * 4 + 1];
  const float A3 = stats2[c * 4 + 2], K_ = stats2[c * 4 + 3];
  const int xb4 = (b * CIN + rep_idx[c]) * IMG / 4;
  const int ob4 = (b * CIN + c) * IMG / 4;
  const int sb4 = (b * REPN + c) * IMG / 4;
  const float4* xp = reinterpret_cast<const float4*>(in) + xb4;
  float4* op = reinterpret_cast<float4*>(out) + ob4;
  const ushort4* l1p = reinterpret_cast<const ushort4*>(L1) + sb4;
  const ushort4* l2p = reinterpret_cast<const ushort4*>(L2) + sb4;
  const ushort4* s3p = reinterpret_cast<const ushort4*>(S3) + sb4;
  #pragma unroll 1
  for (int g = tid; g < 784; g += 256) {
    const float4 x = xp[g];
    const ushort4 a = l1p[g], d2 = l2p[g], d3 = s3p[g];
    float4 y;
    y.x = fmaf(A1, __uint_as_float((unsigned)a.x << 16),
          fmaf(A2, __uint_as_float((unsigned)d2.x << 16),
          fmaf(A3, __uint_as_float((unsigned)d3.x << 16), K_ + x.x)));
    y.y = fmaf(A1, __uint_as_float((unsigned)a.y << 16),
          fmaf(A2, __uint_as_float((unsigned)d2.y << 16),
          fmaf(A3, __uint_as_float((unsigned)d3.y << 16), K_ + x.y)));
    y.z = fmaf(A1, __uint_as_float((unsigned)a.z << 16),
          fmaf(A2, __uint_as_float((unsigned)d2.z << 16),
          fmaf(A3, __uint_as_float((unsigned)d3.z << 16), K_ + x.z)));
    y.w = fmaf(A1, __uint_as_float((unsigned)a.w << 16),
          fmaf(A2, __uint_as_float((unsigned)d2.w << 16),
          fmaf(A3, __uint_as_float((unsigned)d3.w << 16), K_ + x.w)));
    op[g] = y;
  }
}

extern "C" __global__ void sw_prep(const float* __restrict__ w1, const float* __restrict__ w2,
                                   float* __restrict__ wsum) {
  int i = blockIdx.x * 256 + threadIdx.x;
  if (i < 8820) wsum[i] = w1[i] + w2[i];
}

extern "C" __global__ void sw_reduce(
    const float* __restrict__ partial,
    const float* __restrict__ g1, const float* __restrict__ b1,
    const float* __restrict__ g2, const float* __restrict__ b2,
    const float* __restrict__ g3, const float* __restrict__ b3,
    float* __restrict__ stats2) {
  const int c = blockIdx.x;
  const int tid = threadIdx.x;
  __shared__ float sm[6];
  if (tid < 6) {
    float s = 0;
    #pragma unroll
    for (int u = 0; u < 14; ++u) s += partial[(c * 14 + u) * 6 + tid];
    sm[tid] = s;
  }
  __syncthreads();
  if (tid == 0) {
    const float N = 100352.f;
    float m1 = sm[0] / N, v1 = sm[1] / N - m1 * m1;
    float m2 = sm[2] / N, v2 = sm[3] / N - m2 * m2;
    float m3 = sm[4] / N, v3 = sm[5] / N - m3 * m3;
    float A1 = g1[c] * rsqrtf(v1 + 1e-5f);
    float A2 = g2[c] * rsqrtf(v2 + 1e-5f);
    float A3 = g3[c] * rsqrtf(v3 + 1e-5f);
    float K = b1[c] + b2[c] + b3[c] - m1 * A1 - m2 * A2 - m3 * A3;
    stats2[c * 4 + 0] = A1; stats2[c * 4 + 1] = A2;
    stats2[c * 4 + 2] = A3; stats2[c * 4 + 3] = K;
  }
}

extern "C" void kernel_launch(void* const* d_in, const int* in_sizes, int n_in,
                              void* d_out, int out_size, void* d_ws, size_t ws_size,
                              hipStream_t stream) {
  const float* in  = (const float*)d_in[0];
  const float* w1  = (const float*)d_in[1];
  const float* w2  = (const float*)d_in[2];
  const float* g1  = (const float*)d_in[3];
  const float* b1  = (const float*)d_in[4];
  const float* g2  = (const float*)d_in[5];
  const float* b2  = (const float*)d_in[6];
  const float* g3  = (const float*)d_in[7];
  const float* b3  = (const float*)d_in[8];
  const int* ghost_idx = (const int*)d_in[9];
  const int* rep_idx   = (const int*)d_in[10];
  float* out = (float*)d_out;
  float* ws  = (float*)d_ws;

  float* wsum    = ws;          // 8820 floats
  float* stats2  = ws + 8832;   // 784 floats
  float* partial = ws + 9728;   // 196*14*6 = 16464 floats
  unsigned short* L1 = reinterpret_cast<unsigned short*>((char*)d_ws + (1u << 18));
  unsigned short* L2 = L1 + STASH_ELEMS;
  unsigned short* S3 = L2 + STASH_ELEMS;
  const size_t need = (1u << 18) + 3ull * STASH_ELEMS * sizeof(unsigned short);

  sw_prep<<<35, 256, 0, stream>>>(w1, w2, wsum);
  if (ws_size >= need) {
    sw_pass1<true><<<NCONV1, 256, 0, stream>>>(in, rep_idx, wsum, partial, L1, L2, S3);
    sw_reduce<<<196, 64, 0, stream>>>(partial, g1, b1, g2, b2, g3, b3, stats2);
    sw_norm<<<6272 + NGHOSTBLK, 256, 0, stream>>>(in, rep_idx, ghost_idx, stats2,
                                                  L1, L2, S3, out);
  } else {
    sw_pass1<false><<<NCONV1, 256, 0, stream>>>(in, rep_idx, wsum, partial, L1, L2, S3);
    sw_reduce<<<196, 64, 0, stream>>>(partial, g1, b1, g2, b2, g3, b3, stats2);
    sw_pass2r<<<NCONV2R + NGHOSTBLK, 448, 0, stream>>>(in, rep_idx, ghost_idx, wsum,
                                                       stats2, out);
  }
}